// Round 1
// baseline (898.697 us; speedup 1.0000x reference)
//
#include <hip/hip_runtime.h>
#include <cstdint>
#include <cstddef>

#define HW 14400
#define WIDTH 120
#define S_TOT 110

// ---------------------------------------------------------------------------
// Pyramid pooling: in [nplanes][14400] -> out [nplanes][110]
// Pool sizes 1,3,6,8 over 120x120. Common refinement: 24x24 grid of 5x5 sums.
// ---------------------------------------------------------------------------
__global__ __launch_bounds__(256) void pool_kernel(const float* __restrict__ in,
                                                   float* __restrict__ outp) {
  __shared__ float part[576];
  const float* plane = in + (size_t)blockIdx.x * HW;
  int t = threadIdx.x;
  for (int bb = t; bb < 576; bb += 256) {
    int by = bb / 24, bx = bb % 24;
    const float* p0 = plane + (by * 5) * WIDTH + bx * 5;
    float s = 0.f;
#pragma unroll
    for (int yy = 0; yy < 5; ++yy)
#pragma unroll
      for (int xx = 0; xx < 5; ++xx) s += p0[yy * WIDTH + xx];
    part[bb] = s;
  }
  __syncthreads();
  if (t < S_TOT) {
    float s = 0.f;
    if (t == 0) {                      // p=1: whole plane
      for (int i = 0; i < 576; ++i) s += part[i];
      s *= (1.f / 14400.f);
    } else if (t < 10) {               // p=3: 8x8 of 5-blocks
      int idx = t - 1, i = idx / 3, j = idx % 3;
      for (int a = 0; a < 8; ++a)
        for (int c = 0; c < 8; ++c) s += part[(i * 8 + a) * 24 + (j * 8 + c)];
      s *= (1.f / 1600.f);
    } else if (t < 46) {               // p=6: 4x4 of 5-blocks
      int idx = t - 10, i = idx / 6, j = idx % 6;
      for (int a = 0; a < 4; ++a)
        for (int c = 0; c < 4; ++c) s += part[(i * 4 + a) * 24 + (j * 4 + c)];
      s *= (1.f / 400.f);
    } else {                           // p=8: 3x3 of 5-blocks
      int idx = t - 46, i = idx / 8, j = idx % 8;
      for (int a = 0; a < 3; ++a)
        for (int c = 0; c < 3; ++c) s += part[(i * 3 + a) * 24 + (j * 3 + c)];
      s *= (1.f / 225.f);
    }
    outp[(size_t)blockIdx.x * S_TOT + t] = s;
  }
}

#define FMA_ROW(r, av) \
  acc[r][0] += (av) * b4.x; acc[r][1] += (av) * b4.y; \
  acc[r][2] += (av) * b4.z; acc[r][3] += (av) * b4.w;

// ---------------------------------------------------------------------------
// kq = relu(BN(Wk @ x + bk)) : C[b][m][n], M=256, K=512, N=14400 ("NN")
// BM=128 BN=64 BK=16, 256 threads, 8x4 micro-tile.
// ---------------------------------------------------------------------------
__global__ __launch_bounds__(256) void gemm_kq(
    const float* __restrict__ Wm, const float* __restrict__ X, float* __restrict__ C,
    const float* __restrict__ bk, const float* __restrict__ gamma,
    const float* __restrict__ beta, const float* __restrict__ mean,
    const float* __restrict__ var) {
  const int K = 512, M = 256, N = HW;
  __shared__ float Wt[16][132];  // [k][m]
  __shared__ float Xt[16][68];   // [k][n]
  int b = blockIdx.z;
  int m0 = blockIdx.y * 128, n0 = blockIdx.x * 64;
  const float* Xb = X + (size_t)b * K * N;
  int t = threadIdx.x, tm = t >> 4, tn = t & 15;
  int lm = t >> 2, lk = (t & 3) << 2;       // W-tile: rows lm, lm+64
  int lk2 = t >> 4, ln = (t & 15) << 2;     // X-tile
  float acc[8][4] = {};
  for (int k0 = 0; k0 < K; k0 += 16) {
    float4 w0 = *(const float4*)&Wm[(size_t)(m0 + lm) * K + k0 + lk];
    float4 w1 = *(const float4*)&Wm[(size_t)(m0 + lm + 64) * K + k0 + lk];
    float4 x4 = *(const float4*)&Xb[(size_t)(k0 + lk2) * N + n0 + ln];
    Wt[lk + 0][lm] = w0.x; Wt[lk + 1][lm] = w0.y; Wt[lk + 2][lm] = w0.z; Wt[lk + 3][lm] = w0.w;
    Wt[lk + 0][lm + 64] = w1.x; Wt[lk + 1][lm + 64] = w1.y;
    Wt[lk + 2][lm + 64] = w1.z; Wt[lk + 3][lm + 64] = w1.w;
    *(float4*)&Xt[lk2][ln] = x4;
    __syncthreads();
#pragma unroll
    for (int kk = 0; kk < 16; ++kk) {
      float4 a0 = *(const float4*)&Wt[kk][tm * 8];
      float4 a1 = *(const float4*)&Wt[kk][tm * 8 + 4];
      float4 b4 = *(const float4*)&Xt[kk][tn * 4];
      FMA_ROW(0, a0.x) FMA_ROW(1, a0.y) FMA_ROW(2, a0.z) FMA_ROW(3, a0.w)
      FMA_ROW(4, a1.x) FMA_ROW(5, a1.y) FMA_ROW(6, a1.z) FMA_ROW(7, a1.w)
    }
    __syncthreads();
  }
#pragma unroll
  for (int i = 0; i < 8; ++i) {
    int mi = m0 + tm * 8 + i;
    float inv = gamma[mi] / sqrtf(var[mi] + 1e-5f);
    float sh = (bk[mi] - mean[mi]) * inv + beta[mi];
    float4 o;
    o.x = fmaxf(acc[i][0] * inv + sh, 0.f);
    o.y = fmaxf(acc[i][1] * inv + sh, 0.f);
    o.z = fmaxf(acc[i][2] * inv + sh, 0.f);
    o.w = fmaxf(acc[i][3] * inv + sh, 0.f);
    *(float4*)&C[((size_t)(b * M + mi)) * N + n0 + tn * 4] = o;
  }
}

// ---------------------------------------------------------------------------
// out = Wo @ agg + bo : agg is [b][n][k] ("TN"), M=512, K=256, N=14400
// ---------------------------------------------------------------------------
__global__ __launch_bounds__(256) void gemm_out(
    const float* __restrict__ Wm, const float* __restrict__ A, float* __restrict__ C,
    const float* __restrict__ bo) {
  const int K = 256, M = 512, N = HW;
  __shared__ float Wt[16][132];
  __shared__ float Xt[16][68];
  int b = blockIdx.z;
  int m0 = blockIdx.y * 128, n0 = blockIdx.x * 64;
  const float* Ab = A + (size_t)b * (size_t)N * K;
  int t = threadIdx.x, tm = t >> 4, tn = t & 15;
  int lm = t >> 2, lk = (t & 3) << 2;
  float acc[8][4] = {};
  for (int k0 = 0; k0 < K; k0 += 16) {
    float4 w0 = *(const float4*)&Wm[(size_t)(m0 + lm) * K + k0 + lk];
    float4 w1 = *(const float4*)&Wm[(size_t)(m0 + lm + 64) * K + k0 + lk];
    float4 x4 = *(const float4*)&Ab[(size_t)(n0 + lm) * K + k0 + lk];  // row n=lm
    Wt[lk + 0][lm] = w0.x; Wt[lk + 1][lm] = w0.y; Wt[lk + 2][lm] = w0.z; Wt[lk + 3][lm] = w0.w;
    Wt[lk + 0][lm + 64] = w1.x; Wt[lk + 1][lm + 64] = w1.y;
    Wt[lk + 2][lm + 64] = w1.z; Wt[lk + 3][lm + 64] = w1.w;
    Xt[lk + 0][lm] = x4.x; Xt[lk + 1][lm] = x4.y; Xt[lk + 2][lm] = x4.z; Xt[lk + 3][lm] = x4.w;
    __syncthreads();
#pragma unroll
    for (int kk = 0; kk < 16; ++kk) {
      float4 a0 = *(const float4*)&Wt[kk][tm * 8];
      float4 a1 = *(const float4*)&Wt[kk][tm * 8 + 4];
      float4 b4 = *(const float4*)&Xt[kk][tn * 4];
      FMA_ROW(0, a0.x) FMA_ROW(1, a0.y) FMA_ROW(2, a0.z) FMA_ROW(3, a0.w)
      FMA_ROW(4, a1.x) FMA_ROW(5, a1.y) FMA_ROW(6, a1.z) FMA_ROW(7, a1.w)
    }
    __syncthreads();
  }
#pragma unroll
  for (int i = 0; i < 8; ++i) {
    int mi = m0 + tm * 8 + i;
    float bb = bo[mi];
    float4 o;
    o.x = acc[i][0] + bb; o.y = acc[i][1] + bb;
    o.z = acc[i][2] + bb; o.w = acc[i][3] + bb;
    *(float4*)&C[((size_t)(b * M + mi)) * N + n0 + tn * 4] = o;
  }
}

// ---------------------------------------------------------------------------
// value[b][s][cv] = Wv[cv,:] . xp[b,:,s] + bv[cv]   (tiny GEMM: 4x110x256x512)
// one block per (b,s), thread = cv
// ---------------------------------------------------------------------------
__global__ __launch_bounds__(256) void value_kernel(
    const float* __restrict__ Wv, const float* __restrict__ xp,
    const float* __restrict__ bv, float* __restrict__ val) {
  int b = blockIdx.x / S_TOT, s = blockIdx.x % S_TOT;
  __shared__ float xs[512];
  int t = threadIdx.x;
  for (int i = t; i < 512; i += 256) xs[i] = xp[((size_t)b * 512 + i) * S_TOT + s];
  __syncthreads();
  float accv = 0.f;
  const float* w = Wv + (size_t)t * 512;
  for (int k = 0; k < 512; k += 4) {
    float4 w4 = *(const float4*)&w[k];
    accv += w4.x * xs[k] + w4.y * xs[k + 1] + w4.z * xs[k + 2] + w4.w * xs[k + 3];
  }
  val[(size_t)blockIdx.x * 256 + t] = accv + bv[t];
}

// ---------------------------------------------------------------------------
// Fused attention: per (b, 64-pixel tile):
//   scores = (kq_tile^T @ key) / 16 ; softmax rows ; agg = attn @ value
// writes agg[b][pix][cv]
// ---------------------------------------------------------------------------
__global__ __launch_bounds__(256) void attn_kernel(
    const float* __restrict__ kq, const float* __restrict__ keyp,
    const float* __restrict__ value, float* __restrict__ agg) {
  __shared__ float sc[64][113];
  __shared__ float qt[32][64];
  __shared__ float kt[32][112];
  __shared__ float red[4][64];
  __shared__ float rinv[64];
  int b = blockIdx.y;
  int pix0 = blockIdx.x * 64;
  int t = threadIdx.x;

  // ---- stage 1: scores[64][110] over c=256 in chunks of 32 ----
  int pi = t & 7;    // pixel group: pix = pi*8 .. pi*8+7
  int si = t >> 3;   // s lanes: s = si + 32j
  float a[8][4];
#pragma unroll
  for (int p = 0; p < 8; ++p)
#pragma unroll
    for (int j = 0; j < 4; ++j) a[p][j] = 0.f;

  for (int c0 = 0; c0 < 256; c0 += 32) {
#pragma unroll
    for (int u = 0; u < 2; ++u) {  // q tile: 32 c x 64 pix, vectorized
      int fi = t + u * 256;
      int cc = fi >> 4, p4 = (fi & 15) * 4;
      *(float4*)&qt[cc][p4] =
          *(const float4*)&kq[((size_t)(b * 256 + c0 + cc)) * HW + pix0 + p4];
    }
    for (int i = t; i < 32 * S_TOT; i += 256) {  // key tile: 32 c x 110 s
      int cc = i / S_TOT, ss = i % S_TOT;
      kt[cc][ss] = keyp[((size_t)(b * 256 + c0 + cc)) * S_TOT + ss];
    }
    __syncthreads();
    for (int cc = 0; cc < 32; ++cc) {
      float4 q0 = *(const float4*)&qt[cc][pi * 8];
      float4 q1 = *(const float4*)&qt[cc][pi * 8 + 4];
#pragma unroll
      for (int j = 0; j < 4; ++j) {
        int s = si + 32 * j;
        if (s < S_TOT) {
          float kv = kt[cc][s];
          a[0][j] += q0.x * kv; a[1][j] += q0.y * kv;
          a[2][j] += q0.z * kv; a[3][j] += q0.w * kv;
          a[4][j] += q1.x * kv; a[5][j] += q1.y * kv;
          a[6][j] += q1.z * kv; a[7][j] += q1.w * kv;
        }
      }
    }
    __syncthreads();
  }
#pragma unroll
  for (int j = 0; j < 4; ++j) {
    int s = si + 32 * j;
    if (s < S_TOT) {
#pragma unroll
      for (int p = 0; p < 8; ++p) sc[pi * 8 + p][s] = a[p][j] * 0.0625f;
    }
  }
  __syncthreads();

  // ---- stage 2: row softmax (4 threads per row, 28 s each) ----
  int part = t >> 6, r = t & 63;
  int sbeg = part * 28, send = sbeg + 28 < S_TOT ? sbeg + 28 : S_TOT;
  float mx = -1e30f;
  for (int s = sbeg; s < send; ++s) mx = fmaxf(mx, sc[r][s]);
  red[part][r] = mx;
  __syncthreads();
  float m = fmaxf(fmaxf(red[0][r], red[1][r]), fmaxf(red[2][r], red[3][r]));
  float sum = 0.f;
  for (int s = sbeg; s < send; ++s) {
    float e = __expf(sc[r][s] - m);
    sc[r][s] = e;
    sum += e;
  }
  __syncthreads();
  red[part][r] = sum;
  __syncthreads();
  if (part == 0) rinv[r] = 1.f / (red[0][r] + red[1][r] + red[2][r] + red[3][r]);
  __syncthreads();

  // ---- stage 3: agg[64][256] = attn @ value ----
  int tn2 = t & 63, tm2 = t >> 6;
  int cv = tn2 * 4;
  float4 acc4[16];
#pragma unroll
  for (int p = 0; p < 16; ++p) acc4[p] = make_float4(0.f, 0.f, 0.f, 0.f);
  const float* vb = value + (size_t)b * S_TOT * 256 + cv;
  for (int s = 0; s < S_TOT; ++s) {
    float4 v4 = *(const float4*)&vb[(size_t)s * 256];
#pragma unroll
    for (int p = 0; p < 16; ++p) {
      float e = sc[tm2 * 16 + p][s];
      acc4[p].x += e * v4.x; acc4[p].y += e * v4.y;
      acc4[p].z += e * v4.z; acc4[p].w += e * v4.w;
    }
  }
#pragma unroll
  for (int p = 0; p < 16; ++p) {
    int pix = tm2 * 16 + p;
    float iv = rinv[pix];
    float4 o = make_float4(acc4[p].x * iv, acc4[p].y * iv, acc4[p].z * iv, acc4[p].w * iv);
    *(float4*)&agg[((size_t)(b * HW + pix0 + pix)) * 256 + cv] = o;
  }
}

extern "C" void kernel_launch(void* const* d_in, const int* in_sizes, int n_in,
                              void* d_out, int out_size, void* d_ws, size_t ws_size,
                              hipStream_t stream) {
  (void)in_sizes; (void)n_in; (void)out_size; (void)ws_size;
  const float* x     = (const float*)d_in[0];
  const float* Wk    = (const float*)d_in[1];
  const float* bk    = (const float*)d_in[2];
  const float* gamma = (const float*)d_in[3];
  const float* beta  = (const float*)d_in[4];
  const float* mean  = (const float*)d_in[5];
  const float* var   = (const float*)d_in[6];
  const float* Wv    = (const float*)d_in[7];
  const float* bv    = (const float*)d_in[8];
  const float* Wo    = (const float*)d_in[9];
  const float* bo    = (const float*)d_in[10];
  float* out = (float*)d_out;

  float* ws    = (float*)d_ws;
  float* kq    = ws;                                   // 4*256*14400
  float* agg   = kq + (size_t)4 * 256 * HW;            // 4*14400*256
  float* xp    = agg + (size_t)4 * HW * 256;           // 4*512*110
  float* value = xp + (size_t)4 * 512 * S_TOT;         // 4*110*256
  float* keyp  = value + (size_t)4 * S_TOT * 256;      // 4*256*110

  // 1. pyramid-pool x (pooling commutes with the 1x1 conv for value)
  pool_kernel<<<dim3(4 * 512), dim3(256), 0, stream>>>(x, xp);
  // 2. kq = relu(BN(conv_k(x)))
  gemm_kq<<<dim3(225, 2, 4), dim3(256), 0, stream>>>(Wk, x, kq, bk, gamma, beta, mean, var);
  // 3. value = conv_v(pooled x) + bv
  value_kernel<<<dim3(4 * S_TOT), dim3(256), 0, stream>>>(Wv, xp, bv, value);
  // 4. key = ppm(kq)
  pool_kernel<<<dim3(4 * 256), dim3(256), 0, stream>>>(kq, keyp);
  // 5. fused scores -> softmax -> agg
  attn_kernel<<<dim3(225, 4), dim3(256), 0, stream>>>(kq, keyp, value, agg);
  // 6. out = conv_out(agg) + bo
  gemm_out<<<dim3(225, 4, 4), dim3(256), 0, stream>>>(Wo, agg, out, bo);
}

// Round 2
// 645.356 us; speedup vs baseline: 1.3926x; 1.3926x over previous
//
#include <hip/hip_runtime.h>
#include <cstdint>
#include <cstddef>

#define HW 14400
#define WIDTH 120
#define S_TOT 110

typedef unsigned short u16;
typedef __attribute__((ext_vector_type(8))) short bf16x8;
typedef __attribute__((ext_vector_type(4))) float f32x4;

__device__ __forceinline__ u16 f2bf(float x) {
  unsigned u = __float_as_uint(x);
  unsigned r = (u + 0x7fffu + ((u >> 16) & 1u)) >> 16;
  return (u16)r;
}
__device__ __forceinline__ float bf2f(u16 h) {
  return __uint_as_float((unsigned)h << 16);
}

__device__ __forceinline__ void async16(void* lds, const void* g) {
  __builtin_amdgcn_global_load_lds(
      (const __attribute__((address_space(1))) void*)g,
      (__attribute__((address_space(3))) void*)lds, 16, 0, 0);
}

// ---------------------------------------------------------------------------
// Pyramid pooling: in [nplanes][14400] -> out [nplanes][110]
// ---------------------------------------------------------------------------
__global__ __launch_bounds__(256) void pool_kernel(const float* __restrict__ in,
                                                   float* __restrict__ outp) {
  __shared__ float part[576];
  const float* plane = in + (size_t)blockIdx.x * HW;
  int t = threadIdx.x;
  for (int bb = t; bb < 576; bb += 256) {
    int by = bb / 24, bx = bb % 24;
    const float* p0 = plane + (by * 5) * WIDTH + bx * 5;
    float s = 0.f;
#pragma unroll
    for (int yy = 0; yy < 5; ++yy)
#pragma unroll
      for (int xx = 0; xx < 5; ++xx) s += p0[yy * WIDTH + xx];
    part[bb] = s;
  }
  __syncthreads();
  if (t < S_TOT) {
    float s = 0.f;
    if (t == 0) {
      for (int i = 0; i < 576; ++i) s += part[i];
      s *= (1.f / 14400.f);
    } else if (t < 10) {
      int idx = t - 1, i = idx / 3, j = idx % 3;
      for (int a = 0; a < 8; ++a)
        for (int c = 0; c < 8; ++c) s += part[(i * 8 + a) * 24 + (j * 8 + c)];
      s *= (1.f / 1600.f);
    } else if (t < 46) {
      int idx = t - 10, i = idx / 6, j = idx % 6;
      for (int a = 0; a < 4; ++a)
        for (int c = 0; c < 4; ++c) s += part[(i * 4 + a) * 24 + (j * 4 + c)];
      s *= (1.f / 400.f);
    } else {
      int idx = t - 46, i = idx / 8, j = idx % 8;
      for (int a = 0; a < 3; ++a)
        for (int c = 0; c < 3; ++c) s += part[(i * 3 + a) * 24 + (j * 3 + c)];
      s *= (1.f / 225.f);
    }
    outp[(size_t)blockIdx.x * S_TOT + t] = s;
  }
}

// ---------------------------------------------------------------------------
// Split fp32 weight -> bf16 hi/lo (elementwise)
// ---------------------------------------------------------------------------
__global__ __launch_bounds__(256) void convert_w(const float* __restrict__ in,
                                                 u16* __restrict__ hi,
                                                 u16* __restrict__ lo, int n) {
  int i = blockIdx.x * 256 + threadIdx.x;
  if (i < n) {
    float v = in[i];
    u16 h = f2bf(v);
    hi[i] = h;
    lo[i] = f2bf(v - bf2f(h));
  }
}

// ---------------------------------------------------------------------------
// X [b][512][14400] fp32 -> XT hi/lo [b][14400][512] bf16 (transpose + split)
// 64x64 tiles via LDS.
// ---------------------------------------------------------------------------
__global__ __launch_bounds__(256) void convert_x(const float* __restrict__ X,
                                                 u16* __restrict__ xth,
                                                 u16* __restrict__ xtl) {
  __shared__ float ls[64][65];
  int b = blockIdx.z;
  int n0 = blockIdx.x * 64, k0 = blockIdx.y * 64;
  int t = threadIdx.x;
  int rt = t >> 4, c4 = (t & 15) * 4;
#pragma unroll
  for (int rr = 0; rr < 4; ++rr) {
    int kk = rr * 16 + rt;
    float4 v = *(const float4*)&X[((size_t)(b * 512 + k0 + kk)) * HW + n0 + c4];
    ls[kk][c4] = v.x; ls[kk][c4 + 1] = v.y; ls[kk][c4 + 2] = v.z; ls[kk][c4 + 3] = v.w;
  }
  __syncthreads();
#pragma unroll
  for (int rr = 0; rr < 4; ++rr) {
    int nn = rr * 16 + rt;
    float v0 = ls[c4 + 0][nn], v1 = ls[c4 + 1][nn], v2 = ls[c4 + 2][nn], v3 = ls[c4 + 3][nn];
    ushort4 oh, ol;
    oh.x = f2bf(v0); ol.x = f2bf(v0 - bf2f(oh.x));
    oh.y = f2bf(v1); ol.y = f2bf(v1 - bf2f(oh.y));
    oh.z = f2bf(v2); ol.z = f2bf(v2 - bf2f(oh.z));
    oh.w = f2bf(v3); ol.w = f2bf(v3 - bf2f(oh.w));
    size_t idx = ((size_t)(b * HW + n0 + nn)) * 512 + k0 + c4;
    *(ushort4*)&xth[idx] = oh;
    *(ushort4*)&xtl[idx] = ol;
  }
}

// ---------------------------------------------------------------------------
// Split-bf16 MFMA GEMM:  C[b][m][n] = epi( sum_k A[m][k]*B[b][n][k] )
// A: [M_TOT][K] bf16 hi/lo.  B: [b][14400][K] bf16 hi/lo (k-contiguous).
// M-tile 256, N-tile 64, BK=32. 256 threads = 4 waves, wave-tile 64x64.
// acc += Ahi*Bhi + Ahi*Blo + Alo*Bhi  (fp32 split product, drops lo*lo)
// BNRELU: C = relu(acc*inv + shift)  (p0=bk,p1=gamma,p2=beta,p3=mean,p4=var)
// else  : C = acc + bias             (p0=bo)
// ---------------------------------------------------------------------------
template <int K, int M_TOT, bool BNRELU>
__global__ __launch_bounds__(256) void gemm_mfma(
    const u16* __restrict__ Ah, const u16* __restrict__ Al,
    const u16* __restrict__ Bh, const u16* __restrict__ Bl,
    float* __restrict__ C,
    const float* __restrict__ p0, const float* __restrict__ p1,
    const float* __restrict__ p2, const float* __restrict__ p3,
    const float* __restrict__ p4) {
  constexpr int NSTEP = K / 32;
  __shared__ alignas(16) u16 sAh[256 * 32];  // 16KB: [m][k]
  __shared__ alignas(16) u16 sAl[256 * 32];  // 16KB
  __shared__ alignas(16) u16 sBh[64 * 32];   // 4KB: [n][k]
  __shared__ alignas(16) u16 sBl[64 * 32];   // 4KB
  __shared__ float sP0[256], sP1[256];

  int t = threadIdx.x, w = t >> 6, l = t & 63;
  int b = blockIdx.z;
  int n0 = blockIdx.x * 64;
  int m0 = blockIdx.y * 256;

  if (BNRELU) {
    int m = m0 + t;
    float iv = p1[m] * rsqrtf(p4[m] + 1e-5f);
    sP0[t] = iv;
    sP1[t] = (p0[m] - p3[m]) * iv + p2[m];
  } else {
    sP0[t] = p0[m0 + t];
  }

  int crow = l >> 2;           // row within 16-row chunk
  int cbyte = (l & 3) * 16;    // byte offset within 64B row
  const size_t bOff = (size_t)b * HW;

  f32x4 acc[4][4];
#pragma unroll
  for (int i = 0; i < 4; ++i)
#pragma unroll
    for (int j = 0; j < 4; ++j) acc[i][j] = (f32x4){0.f, 0.f, 0.f, 0.f};

  int fr = l & 15, fk = (l >> 4) * 8;

  for (int ks = 0; ks < NSTEP; ++ks) {
    int k0 = ks * 32;
    // stage 40KB: 40 chunks of 1KB (16 rows x 64B), 10 per wave
#pragma unroll
    for (int c = 0; c < 10; ++c) {
      int i = w * 10 + c;
      const u16* g;
      u16* d;
      if (i < 16) {
        g = Ah + (size_t)(m0 + i * 16 + crow) * K + k0;
        d = sAh + i * 512;
      } else if (i < 32) {
        g = Al + (size_t)(m0 + (i - 16) * 16 + crow) * K + k0;
        d = sAl + (i - 16) * 512;
      } else if (i < 36) {
        g = Bh + (bOff + n0 + (i - 32) * 16 + crow) * K + k0;
        d = sBh + (i - 32) * 512;
      } else {
        g = Bl + (bOff + n0 + (i - 36) * 16 + crow) * K + k0;
        d = sBl + (i - 36) * 512;
      }
      async16((char*)d, (const char*)g + cbyte);
    }
    __syncthreads();

    bf16x8 ah[4], al[4], bh[4], bl[4];
#pragma unroll
    for (int mt = 0; mt < 4; ++mt) {
      int r = w * 64 + mt * 16 + fr;
      ah[mt] = *(const bf16x8*)&sAh[r * 32 + fk];
      al[mt] = *(const bf16x8*)&sAl[r * 32 + fk];
    }
#pragma unroll
    for (int nt = 0; nt < 4; ++nt) {
      int r = nt * 16 + fr;
      bh[nt] = *(const bf16x8*)&sBh[r * 32 + fk];
      bl[nt] = *(const bf16x8*)&sBl[r * 32 + fk];
    }
#pragma unroll
    for (int mt = 0; mt < 4; ++mt)
#pragma unroll
      for (int nt = 0; nt < 4; ++nt) {
        acc[mt][nt] = __builtin_amdgcn_mfma_f32_16x16x32_bf16(ah[mt], bh[nt], acc[mt][nt], 0, 0, 0);
        acc[mt][nt] = __builtin_amdgcn_mfma_f32_16x16x32_bf16(ah[mt], bl[nt], acc[mt][nt], 0, 0, 0);
        acc[mt][nt] = __builtin_amdgcn_mfma_f32_16x16x32_bf16(al[mt], bh[nt], acc[mt][nt], 0, 0, 0);
      }
    __syncthreads();
  }

  // epilogue: C/D layout col = l&15 (n), row = (l>>4)*4 + reg (m)
#pragma unroll
  for (int mt = 0; mt < 4; ++mt) {
    int lmBase = w * 64 + mt * 16 + (l >> 4) * 4;
#pragma unroll
    for (int nt = 0; nt < 4; ++nt) {
      int n = n0 + nt * 16 + fr;
#pragma unroll
      for (int r = 0; r < 4; ++r) {
        int lm = lmBase + r;
        float v = acc[mt][nt][r];
        if (BNRELU)
          v = fmaxf(v * sP0[lm] + sP1[lm], 0.f);
        else
          v = v + sP0[lm];
        C[((size_t)(b * M_TOT + m0 + lm)) * HW + n] = v;
      }
    }
  }
}

// ---------------------------------------------------------------------------
// value[b][s][cv] = Wv[cv,:] . xp[b,:,s] + bv[cv]
// ---------------------------------------------------------------------------
__global__ __launch_bounds__(256) void value_kernel(
    const float* __restrict__ Wv, const float* __restrict__ xp,
    const float* __restrict__ bv, float* __restrict__ val) {
  int b = blockIdx.x / S_TOT, s = blockIdx.x % S_TOT;
  __shared__ float xs[512];
  int t = threadIdx.x;
  for (int i = t; i < 512; i += 256) xs[i] = xp[((size_t)b * 512 + i) * S_TOT + s];
  __syncthreads();
  float accv = 0.f;
  const float* w = Wv + (size_t)t * 512;
  for (int k = 0; k < 512; k += 4) {
    float4 w4 = *(const float4*)&w[k];
    accv += w4.x * xs[k] + w4.y * xs[k + 1] + w4.z * xs[k + 2] + w4.w * xs[k + 3];
  }
  val[(size_t)blockIdx.x * 256 + t] = accv + bv[t];
}

// ---------------------------------------------------------------------------
// Fused attention; writes agg as split bf16 hi/lo [b][pix][256]
// ---------------------------------------------------------------------------
__global__ __launch_bounds__(256) void attn_kernel(
    const float* __restrict__ kq, const float* __restrict__ keyp,
    const float* __restrict__ value, u16* __restrict__ aggh,
    u16* __restrict__ aggl) {
  __shared__ float sc[64][113];
  __shared__ float qt[32][64];
  __shared__ float kt[32][112];
  __shared__ float red[4][64];
  __shared__ float rinv[64];
  int b = blockIdx.y;
  int pix0 = blockIdx.x * 64;
  int t = threadIdx.x;

  // ---- stage 1: scores[64][110] over c=256 in chunks of 32 ----
  int pi = t & 7;
  int si = t >> 3;
  float a[8][4];
#pragma unroll
  for (int p = 0; p < 8; ++p)
#pragma unroll
    for (int j = 0; j < 4; ++j) a[p][j] = 0.f;

  for (int c0 = 0; c0 < 256; c0 += 32) {
#pragma unroll
    for (int u = 0; u < 2; ++u) {
      int fi = t + u * 256;
      int cc = fi >> 4, p4 = (fi & 15) * 4;
      *(float4*)&qt[cc][p4] =
          *(const float4*)&kq[((size_t)(b * 256 + c0 + cc)) * HW + pix0 + p4];
    }
    for (int i = t; i < 32 * S_TOT; i += 256) {
      int cc = i / S_TOT, ss = i % S_TOT;
      kt[cc][ss] = keyp[((size_t)(b * 256 + c0 + cc)) * S_TOT + ss];
    }
    __syncthreads();
    for (int cc = 0; cc < 32; ++cc) {
      float4 q0 = *(const float4*)&qt[cc][pi * 8];
      float4 q1 = *(const float4*)&qt[cc][pi * 8 + 4];
#pragma unroll
      for (int j = 0; j < 4; ++j) {
        int s = si + 32 * j;
        if (s < S_TOT) {
          float kv = kt[cc][s];
          a[0][j] += q0.x * kv; a[1][j] += q0.y * kv;
          a[2][j] += q0.z * kv; a[3][j] += q0.w * kv;
          a[4][j] += q1.x * kv; a[5][j] += q1.y * kv;
          a[6][j] += q1.z * kv; a[7][j] += q1.w * kv;
        }
      }
    }
    __syncthreads();
  }
#pragma unroll
  for (int j = 0; j < 4; ++j) {
    int s = si + 32 * j;
    if (s < S_TOT) {
#pragma unroll
      for (int p = 0; p < 8; ++p) sc[pi * 8 + p][s] = a[p][j] * 0.0625f;
    }
  }
  __syncthreads();

  // ---- stage 2: row softmax ----
  int part = t >> 6, r = t & 63;
  int sbeg = part * 28, send = sbeg + 28 < S_TOT ? sbeg + 28 : S_TOT;
  float mx = -1e30f;
  for (int s = sbeg; s < send; ++s) mx = fmaxf(mx, sc[r][s]);
  red[part][r] = mx;
  __syncthreads();
  float m = fmaxf(fmaxf(red[0][r], red[1][r]), fmaxf(red[2][r], red[3][r]));
  float sum = 0.f;
  for (int s = sbeg; s < send; ++s) {
    float e = __expf(sc[r][s] - m);
    sc[r][s] = e;
    sum += e;
  }
  __syncthreads();
  red[part][r] = sum;
  __syncthreads();
  if (part == 0) rinv[r] = 1.f / (red[0][r] + red[1][r] + red[2][r] + red[3][r]);
  __syncthreads();

  // ---- stage 3: agg[64][256] = attn @ value, store split bf16 ----
  int tn2 = t & 63, tm2 = t >> 6;
  int cv = tn2 * 4;
  float4 acc4[16];
#pragma unroll
  for (int p = 0; p < 16; ++p) acc4[p] = make_float4(0.f, 0.f, 0.f, 0.f);
  const float* vb = value + (size_t)b * S_TOT * 256 + cv;
  for (int s = 0; s < S_TOT; ++s) {
    float4 v4 = *(const float4*)&vb[(size_t)s * 256];
#pragma unroll
    for (int p = 0; p < 16; ++p) {
      float e = sc[tm2 * 16 + p][s];
      acc4[p].x += e * v4.x; acc4[p].y += e * v4.y;
      acc4[p].z += e * v4.z; acc4[p].w += e * v4.w;
    }
  }
#pragma unroll
  for (int p = 0; p < 16; ++p) {
    int pix = tm2 * 16 + p;
    float iv = rinv[pix];
    float v0 = acc4[p].x * iv, v1 = acc4[p].y * iv, v2 = acc4[p].z * iv, v3 = acc4[p].w * iv;
    ushort4 oh, ol;
    oh.x = f2bf(v0); ol.x = f2bf(v0 - bf2f(oh.x));
    oh.y = f2bf(v1); ol.y = f2bf(v1 - bf2f(oh.y));
    oh.z = f2bf(v2); ol.z = f2bf(v2 - bf2f(oh.z));
    oh.w = f2bf(v3); ol.w = f2bf(v3 - bf2f(oh.w));
    size_t base = ((size_t)(b * HW + pix0 + pix)) * 256 + cv;
    *(ushort4*)&aggh[base] = oh;
    *(ushort4*)&aggl[base] = ol;
  }
}

extern "C" void kernel_launch(void* const* d_in, const int* in_sizes, int n_in,
                              void* d_out, int out_size, void* d_ws, size_t ws_size,
                              hipStream_t stream) {
  (void)in_sizes; (void)n_in; (void)out_size; (void)ws_size;
  const float* x     = (const float*)d_in[0];
  const float* Wk    = (const float*)d_in[1];
  const float* bk    = (const float*)d_in[2];
  const float* gamma = (const float*)d_in[3];
  const float* beta  = (const float*)d_in[4];
  const float* mean  = (const float*)d_in[5];
  const float* var   = (const float*)d_in[6];
  const float* Wv    = (const float*)d_in[7];
  const float* bv    = (const float*)d_in[8];
  const float* Wo    = (const float*)d_in[9];
  const float* bo    = (const float*)d_in[10];
  float* out = (float*)d_out;

  char* p = (char*)d_ws;
  float* kq = (float*)p;      p += (size_t)14745600 * 4;   // 4*256*14400 fp32
  u16* xth = (u16*)p;         p += (size_t)29491200 * 2;   // 4*14400*512 bf16
  u16* xtl = (u16*)p;         p += (size_t)29491200 * 2;
  u16* wkh = (u16*)p;         p += 131072 * 2;
  u16* wkl = (u16*)p;         p += 131072 * 2;
  u16* woh = (u16*)p;         p += 131072 * 2;
  u16* wol = (u16*)p;         p += 131072 * 2;
  float* xp = (float*)p;      p += (size_t)4 * 512 * 110 * 4;
  float* value = (float*)p;   p += (size_t)4 * 110 * 256 * 4;
  float* keyp = (float*)p;    p += (size_t)4 * 256 * 110 * 4;
  // agg hi/lo alias the XT buffers (XT dead after gemm_kq; attn runs after)
  u16* aggh = xth;            // 4*14400*256 bf16
  u16* aggl = xtl;

  // weight splits (tiny)
  convert_w<<<512, 256, 0, stream>>>(Wk, wkh, wkl, 256 * 512);
  convert_w<<<512, 256, 0, stream>>>(Wo, woh, wol, 512 * 256);
  // X -> transposed bf16 hi/lo
  convert_x<<<dim3(225, 8, 4), 256, 0, stream>>>(x, xth, xtl);
  // pyramid-pool x (pooling commutes with 1x1 conv for value)
  pool_kernel<<<dim3(4 * 512), dim3(256), 0, stream>>>(x, xp);
  // value = conv_v(pooled x) + bv
  value_kernel<<<dim3(4 * S_TOT), dim3(256), 0, stream>>>(Wv, xp, bv, value);
  // kq = relu(BN(conv_k(x)))  [split-bf16 MFMA]
  gemm_mfma<512, 256, true><<<dim3(225, 1, 4), 256, 0, stream>>>(
      wkh, wkl, xth, xtl, kq, bk, gamma, beta, mean, var);
  // key = ppm(kq)
  pool_kernel<<<dim3(4 * 256), dim3(256), 0, stream>>>(kq, keyp);
  // fused scores -> softmax -> agg (bf16 hi/lo out)
  attn_kernel<<<dim3(225, 4), 256, 0, stream>>>(kq, keyp, value, aggh, aggl);
  // out = conv_out(agg) + bo  [split-bf16 MFMA]
  gemm_mfma<256, 512, false><<<dim3(225, 2, 4), 256, 0, stream>>>(
      woh, wol, aggh, aggl, out, bo, nullptr, nullptr, nullptr, nullptr);
}

// Round 3
// 619.498 us; speedup vs baseline: 1.4507x; 1.0417x over previous
//
#include <hip/hip_runtime.h>
#include <cstdint>
#include <cstddef>

#define HW 14400
#define WIDTH 120
#define S_TOT 110

typedef unsigned short u16;
typedef __attribute__((ext_vector_type(8))) short bf16x8;
typedef __attribute__((ext_vector_type(4))) float f32x4;

__device__ __forceinline__ u16 f2bf(float x) {
  unsigned u = __float_as_uint(x);
  unsigned r = (u + 0x7fffu + ((u >> 16) & 1u)) >> 16;
  return (u16)r;
}
__device__ __forceinline__ float bf2f(u16 h) {
  return __uint_as_float((unsigned)h << 16);
}

__device__ __forceinline__ void async16(void* lds, const void* g) {
  __builtin_amdgcn_global_load_lds(
      (const __attribute__((address_space(1))) void*)g,
      (__attribute__((address_space(3))) void*)lds, 16, 0, 0);
}

// ---------------------------------------------------------------------------
// Pyramid pooling: in [nplanes][14400] -> out [nplanes][110]
// ---------------------------------------------------------------------------
__global__ __launch_bounds__(256) void pool_kernel(const float* __restrict__ in,
                                                   float* __restrict__ outp) {
  __shared__ float part[576];
  const float* plane = in + (size_t)blockIdx.x * HW;
  int t = threadIdx.x;
  for (int bb = t; bb < 576; bb += 256) {
    int by = bb / 24, bx = bb % 24;
    const float* p0 = plane + (by * 5) * WIDTH + bx * 5;
    float s = 0.f;
#pragma unroll
    for (int yy = 0; yy < 5; ++yy)
#pragma unroll
      for (int xx = 0; xx < 5; ++xx) s += p0[yy * WIDTH + xx];
    part[bb] = s;
  }
  __syncthreads();
  if (t < S_TOT) {
    float s = 0.f;
    if (t == 0) {
      for (int i = 0; i < 576; ++i) s += part[i];
      s *= (1.f / 14400.f);
    } else if (t < 10) {
      int idx = t - 1, i = idx / 3, j = idx % 3;
      for (int a = 0; a < 8; ++a)
        for (int c = 0; c < 8; ++c) s += part[(i * 8 + a) * 24 + (j * 8 + c)];
      s *= (1.f / 1600.f);
    } else if (t < 46) {
      int idx = t - 10, i = idx / 6, j = idx % 6;
      for (int a = 0; a < 4; ++a)
        for (int c = 0; c < 4; ++c) s += part[(i * 4 + a) * 24 + (j * 4 + c)];
      s *= (1.f / 400.f);
    } else {
      int idx = t - 46, i = idx / 8, j = idx % 8;
      for (int a = 0; a < 3; ++a)
        for (int c = 0; c < 3; ++c) s += part[(i * 3 + a) * 24 + (j * 3 + c)];
      s *= (1.f / 225.f);
    }
    outp[(size_t)blockIdx.x * S_TOT + t] = s;
  }
}

// ---------------------------------------------------------------------------
// Split fp32 weight -> bf16 hi/lo (elementwise)
// ---------------------------------------------------------------------------
__global__ __launch_bounds__(256) void convert_w(const float* __restrict__ in,
                                                 u16* __restrict__ hi,
                                                 u16* __restrict__ lo, int n) {
  int i = blockIdx.x * 256 + threadIdx.x;
  if (i < n) {
    float v = in[i];
    u16 h = f2bf(v);
    hi[i] = h;
    lo[i] = f2bf(v - bf2f(h));
  }
}

// ---------------------------------------------------------------------------
// X [b][CIN][14400] fp32 -> XT hi/lo [b][14400][CIN] bf16 (transpose + split)
// ---------------------------------------------------------------------------
template <int CIN>
__global__ __launch_bounds__(256) void convert_t(const float* __restrict__ X,
                                                 u16* __restrict__ xth,
                                                 u16* __restrict__ xtl) {
  __shared__ float ls[64][65];
  int b = blockIdx.z;
  int n0 = blockIdx.x * 64, k0 = blockIdx.y * 64;
  int t = threadIdx.x;
  int rt = t >> 4, c4 = (t & 15) * 4;
#pragma unroll
  for (int rr = 0; rr < 4; ++rr) {
    int kk = rr * 16 + rt;
    float4 v = *(const float4*)&X[((size_t)(b * CIN + k0 + kk)) * HW + n0 + c4];
    ls[kk][c4] = v.x; ls[kk][c4 + 1] = v.y; ls[kk][c4 + 2] = v.z; ls[kk][c4 + 3] = v.w;
  }
  __syncthreads();
#pragma unroll
  for (int rr = 0; rr < 4; ++rr) {
    int nn = rr * 16 + rt;
    float v0 = ls[c4 + 0][nn], v1 = ls[c4 + 1][nn], v2 = ls[c4 + 2][nn], v3 = ls[c4 + 3][nn];
    ushort4 oh, ol;
    oh.x = f2bf(v0); ol.x = f2bf(v0 - bf2f(oh.x));
    oh.y = f2bf(v1); ol.y = f2bf(v1 - bf2f(oh.y));
    oh.z = f2bf(v2); ol.z = f2bf(v2 - bf2f(oh.z));
    oh.w = f2bf(v3); ol.w = f2bf(v3 - bf2f(oh.w));
    size_t idx = ((size_t)(b * HW + n0 + nn)) * CIN + k0 + c4;
    *(ushort4*)&xth[idx] = oh;
    *(ushort4*)&xtl[idx] = ol;
  }
}

// ---------------------------------------------------------------------------
// Split-bf16 MFMA GEMM:  C[b][m][n] = epi( sum_k A[m][k]*B[b][n][k] )
// (verified round 2)
// ---------------------------------------------------------------------------
template <int K, int M_TOT, bool BNRELU>
__global__ __launch_bounds__(256) void gemm_mfma(
    const u16* __restrict__ Ah, const u16* __restrict__ Al,
    const u16* __restrict__ Bh, const u16* __restrict__ Bl,
    float* __restrict__ C,
    const float* __restrict__ p0, const float* __restrict__ p1,
    const float* __restrict__ p2, const float* __restrict__ p3,
    const float* __restrict__ p4) {
  constexpr int NSTEP = K / 32;
  __shared__ alignas(16) u16 sAh[256 * 32];
  __shared__ alignas(16) u16 sAl[256 * 32];
  __shared__ alignas(16) u16 sBh[64 * 32];
  __shared__ alignas(16) u16 sBl[64 * 32];
  __shared__ float sP0[256], sP1[256];

  int t = threadIdx.x, w = t >> 6, l = t & 63;
  int b = blockIdx.z;
  int n0 = blockIdx.x * 64;
  int m0 = blockIdx.y * 256;

  if (BNRELU) {
    int m = m0 + t;
    float iv = p1[m] * rsqrtf(p4[m] + 1e-5f);
    sP0[t] = iv;
    sP1[t] = (p0[m] - p3[m]) * iv + p2[m];
  } else {
    sP0[t] = p0[m0 + t];
  }

  int crow = l >> 2;
  int cbyte = (l & 3) * 16;
  const size_t bOff = (size_t)b * HW;

  f32x4 acc[4][4];
#pragma unroll
  for (int i = 0; i < 4; ++i)
#pragma unroll
    for (int j = 0; j < 4; ++j) acc[i][j] = (f32x4){0.f, 0.f, 0.f, 0.f};

  int fr = l & 15, fk = (l >> 4) * 8;

  for (int ks = 0; ks < NSTEP; ++ks) {
    int k0 = ks * 32;
#pragma unroll
    for (int c = 0; c < 10; ++c) {
      int i = w * 10 + c;
      const u16* g;
      u16* d;
      if (i < 16) {
        g = Ah + (size_t)(m0 + i * 16 + crow) * K + k0;
        d = sAh + i * 512;
      } else if (i < 32) {
        g = Al + (size_t)(m0 + (i - 16) * 16 + crow) * K + k0;
        d = sAl + (i - 16) * 512;
      } else if (i < 36) {
        g = Bh + (bOff + n0 + (i - 32) * 16 + crow) * K + k0;
        d = sBh + (i - 32) * 512;
      } else {
        g = Bl + (bOff + n0 + (i - 36) * 16 + crow) * K + k0;
        d = sBl + (i - 36) * 512;
      }
      async16((char*)d, (const char*)g + cbyte);
    }
    __syncthreads();

    bf16x8 ah[4], al[4], bh[4], bl[4];
#pragma unroll
    for (int mt = 0; mt < 4; ++mt) {
      int r = w * 64 + mt * 16 + fr;
      ah[mt] = *(const bf16x8*)&sAh[r * 32 + fk];
      al[mt] = *(const bf16x8*)&sAl[r * 32 + fk];
    }
#pragma unroll
    for (int nt = 0; nt < 4; ++nt) {
      int r = nt * 16 + fr;
      bh[nt] = *(const bf16x8*)&sBh[r * 32 + fk];
      bl[nt] = *(const bf16x8*)&sBl[r * 32 + fk];
    }
#pragma unroll
    for (int mt = 0; mt < 4; ++mt)
#pragma unroll
      for (int nt = 0; nt < 4; ++nt) {
        acc[mt][nt] = __builtin_amdgcn_mfma_f32_16x16x32_bf16(ah[mt], bh[nt], acc[mt][nt], 0, 0, 0);
        acc[mt][nt] = __builtin_amdgcn_mfma_f32_16x16x32_bf16(ah[mt], bl[nt], acc[mt][nt], 0, 0, 0);
        acc[mt][nt] = __builtin_amdgcn_mfma_f32_16x16x32_bf16(al[mt], bh[nt], acc[mt][nt], 0, 0, 0);
      }
    __syncthreads();
  }

#pragma unroll
  for (int mt = 0; mt < 4; ++mt) {
    int lmBase = w * 64 + mt * 16 + (l >> 4) * 4;
#pragma unroll
    for (int nt = 0; nt < 4; ++nt) {
      int n = n0 + nt * 16 + fr;
#pragma unroll
      for (int r = 0; r < 4; ++r) {
        int lm = lmBase + r;
        float v = acc[mt][nt][r];
        if (BNRELU)
          v = fmaxf(v * sP0[lm] + sP1[lm], 0.f);
        else
          v = v + sP0[lm];
        C[((size_t)(b * M_TOT + m0 + lm)) * HW + n] = v;
      }
    }
  }
}

// ---------------------------------------------------------------------------
// valueT[b][cv][128] hi/lo = Wv[cv,:] . xp[b,:,s] + bv[cv]  (s>=110 -> 0)
// ---------------------------------------------------------------------------
__global__ __launch_bounds__(256) void value_kernel(
    const float* __restrict__ Wv, const float* __restrict__ xp,
    const float* __restrict__ bv, u16* __restrict__ vth,
    u16* __restrict__ vtl) {
  int b = blockIdx.x >> 7, s = blockIdx.x & 127;
  int t = threadIdx.x;
  size_t o = ((size_t)(b * 256 + t)) * 128 + s;
  if (s >= S_TOT) { vth[o] = 0; vtl[o] = 0; return; }
  __shared__ float xs[512];
  for (int i = t; i < 512; i += 256) xs[i] = xp[((size_t)b * 512 + i) * S_TOT + s];
  __syncthreads();
  float accv = 0.f;
  const float* wv = Wv + (size_t)t * 512;
  for (int k = 0; k < 512; k += 4) {
    float4 w4 = *(const float4*)&wv[k];
    accv += w4.x * xs[k] + w4.y * xs[k + 1] + w4.z * xs[k + 2] + w4.w * xs[k + 3];
  }
  accv += bv[t];
  u16 h = f2bf(accv);
  vth[o] = h;
  vtl[o] = f2bf(accv - bf2f(h));
}

// ---------------------------------------------------------------------------
// keypT[b][128][256] hi/lo from keyp [b][256][110] fp32 (s>=110 -> 0)
// ---------------------------------------------------------------------------
__global__ __launch_bounds__(256) void convert_key(const float* __restrict__ keyp,
                                                   u16* __restrict__ kth,
                                                   u16* __restrict__ ktl) {
  int b = blockIdx.x;
  int t = threadIdx.x;
  for (int i = t; i < 128 * 256; i += 256) {
    int s = i >> 8, c = i & 255;
    float v = (s < S_TOT) ? keyp[((size_t)(b * 256 + c)) * S_TOT + s] : 0.f;
    u16 h = f2bf(v);
    size_t o = ((size_t)(b * 128 + s)) * 256 + c;
    kth[o] = h;
    ktl[o] = f2bf(v - bf2f(h));
  }
}

// ---------------------------------------------------------------------------
// MFMA attention. Per block: 64 pixels, wave w owns pixels w*16..w*16+15.
// Stage 1: S = Q K^T via split-bf16 MFMA (Q frags from kqT, K frags from
// keypT, both global). Softmax fully in-wave (shfl_xor over low-4 lane bits),
// 1/sum folded into P. P -> LDS bf16 hi/lo [64][136] (s padded to 128).
// Stage 2: agg = P V via split-bf16 MFMA (V frags from valueT, global).
// agg written as split bf16 [b][pix][256] (gemm_out's B layout).
// ---------------------------------------------------------------------------
__global__ __launch_bounds__(256) void attn_mfma(
    const u16* __restrict__ qh, const u16* __restrict__ ql,
    const u16* __restrict__ kh, const u16* __restrict__ kl,
    const u16* __restrict__ vh, const u16* __restrict__ vl,
    u16* __restrict__ aggh, u16* __restrict__ aggl) {
  __shared__ u16 Ph[64][136];
  __shared__ u16 Pl[64][136];
  int b = blockIdx.y, pix0 = blockIdx.x * 64;
  int t = threadIdx.x, w = t >> 6, l = t & 63;
  int fr = l & 15, q = l >> 4, fk = q * 8;

  // ---- stage 1: scores [16 pix][112 s] per wave ----
  f32x4 acc[7];
#pragma unroll
  for (int st = 0; st < 7; ++st) acc[st] = (f32x4){0.f, 0.f, 0.f, 0.f};

  const u16* qbh = qh + ((size_t)(b * HW + pix0 + w * 16 + fr)) * 256 + fk;
  const u16* qbl = ql + ((size_t)(b * HW + pix0 + w * 16 + fr)) * 256 + fk;
  const u16* kbh = kh + ((size_t)(b * 128 + fr)) * 256 + fk;
  const u16* kbl = kl + ((size_t)(b * 128 + fr)) * 256 + fk;

  for (int c0 = 0; c0 < 256; c0 += 32) {
    bf16x8 ah = *(const bf16x8*)(qbh + c0);
    bf16x8 al = *(const bf16x8*)(qbl + c0);
#pragma unroll
    for (int st = 0; st < 7; ++st) {
      bf16x8 bh = *(const bf16x8*)(kbh + (size_t)st * 16 * 256 + c0);
      bf16x8 bl = *(const bf16x8*)(kbl + (size_t)st * 16 * 256 + c0);
      acc[st] = __builtin_amdgcn_mfma_f32_16x16x32_bf16(ah, bh, acc[st], 0, 0, 0);
      acc[st] = __builtin_amdgcn_mfma_f32_16x16x32_bf16(ah, bl, acc[st], 0, 0, 0);
      acc[st] = __builtin_amdgcn_mfma_f32_16x16x32_bf16(al, bh, acc[st], 0, 0, 0);
    }
  }

  // scale + mask (lane col = s = st*16+fr; s>=110 only at st==6, fr>=14)
#pragma unroll
  for (int st = 0; st < 7; ++st)
#pragma unroll
    for (int r = 0; r < 4; ++r) acc[st][r] *= 0.0625f;
  if (fr >= 14) {
#pragma unroll
    for (int r = 0; r < 4; ++r) acc[6][r] = -1e30f;
  }

  // in-wave softmax per pixel row (row = q*4+r; cols spread over fr lanes)
#pragma unroll
  for (int r = 0; r < 4; ++r) {
    float m = -1e30f;
#pragma unroll
    for (int st = 0; st < 7; ++st) m = fmaxf(m, acc[st][r]);
    m = fmaxf(m, __shfl_xor(m, 1));
    m = fmaxf(m, __shfl_xor(m, 2));
    m = fmaxf(m, __shfl_xor(m, 4));
    m = fmaxf(m, __shfl_xor(m, 8));
    float s = 0.f;
#pragma unroll
    for (int st = 0; st < 7; ++st) {
      float e = __expf(acc[st][r] - m);
      acc[st][r] = e;
      s += e;
    }
    s += __shfl_xor(s, 1);
    s += __shfl_xor(s, 2);
    s += __shfl_xor(s, 4);
    s += __shfl_xor(s, 8);
    float inv = 1.f / s;
#pragma unroll
    for (int st = 0; st < 7; ++st) acc[st][r] *= inv;
  }

  // write P (normalized) to LDS as split bf16
  int prow = w * 16 + q * 4;
#pragma unroll
  for (int st = 0; st < 7; ++st) {
    int s = st * 16 + fr;
#pragma unroll
    for (int r = 0; r < 4; ++r) {
      float v = acc[st][r];
      u16 h = f2bf(v);
      Ph[prow + r][s] = h;
      Pl[prow + r][s] = f2bf(v - bf2f(h));
    }
  }
  // zero pad s = 112..127
  for (int i = t; i < 64 * 16; i += 256) {
    int rr = i >> 4, ss = 112 + (i & 15);
    Ph[rr][ss] = 0;
    Pl[rr][ss] = 0;
  }
  __syncthreads();

  // ---- stage 2: agg [16 pix][256 cv] per wave ----
  f32x4 oacc[16];
#pragma unroll
  for (int nt = 0; nt < 16; ++nt) oacc[nt] = (f32x4){0.f, 0.f, 0.f, 0.f};

  const u16* vbh = vh + ((size_t)(b * 256 + fr)) * 128 + fk;
  const u16* vbl = vl + ((size_t)(b * 256 + fr)) * 128 + fk;

#pragma unroll
  for (int kc = 0; kc < 4; ++kc) {
    bf16x8 ah = *(const bf16x8*)&Ph[w * 16 + fr][kc * 32 + fk];
    bf16x8 al = *(const bf16x8*)&Pl[w * 16 + fr][kc * 32 + fk];
#pragma unroll
    for (int nt = 0; nt < 16; ++nt) {
      bf16x8 bh = *(const bf16x8*)(vbh + (size_t)nt * 16 * 128 + kc * 32);
      bf16x8 bl = *(const bf16x8*)(vbl + (size_t)nt * 16 * 128 + kc * 32);
      oacc[nt] = __builtin_amdgcn_mfma_f32_16x16x32_bf16(ah, bh, oacc[nt], 0, 0, 0);
      oacc[nt] = __builtin_amdgcn_mfma_f32_16x16x32_bf16(ah, bl, oacc[nt], 0, 0, 0);
      oacc[nt] = __builtin_amdgcn_mfma_f32_16x16x32_bf16(al, bh, oacc[nt], 0, 0, 0);
    }
  }

  // write agg split bf16: pix = w*16+q*4+r, cv = nt*16+fr
#pragma unroll
  for (int nt = 0; nt < 16; ++nt) {
    int cv = nt * 16 + fr;
#pragma unroll
    for (int r = 0; r < 4; ++r) {
      int pix = pix0 + w * 16 + q * 4 + r;
      float v = oacc[nt][r];
      u16 h = f2bf(v);
      size_t o = ((size_t)(b * HW + pix)) * 256 + cv;
      aggh[o] = h;
      aggl[o] = f2bf(v - bf2f(h));
    }
  }
}

extern "C" void kernel_launch(void* const* d_in, const int* in_sizes, int n_in,
                              void* d_out, int out_size, void* d_ws, size_t ws_size,
                              hipStream_t stream) {
  (void)in_sizes; (void)n_in; (void)out_size; (void)ws_size;
  const float* x     = (const float*)d_in[0];
  const float* Wk    = (const float*)d_in[1];
  const float* bk    = (const float*)d_in[2];
  const float* gamma = (const float*)d_in[3];
  const float* beta  = (const float*)d_in[4];
  const float* mean  = (const float*)d_in[5];
  const float* var   = (const float*)d_in[6];
  const float* Wv    = (const float*)d_in[7];
  const float* bv    = (const float*)d_in[8];
  const float* Wo    = (const float*)d_in[9];
  const float* bo    = (const float*)d_in[10];
  float* out = (float*)d_out;

  char* p = (char*)d_ws;
  float* kq = (float*)p;      p += (size_t)14745600 * 4;   // 4*256*14400 fp32
  u16* xth = (u16*)p;         p += (size_t)29491200 * 2;   // 4*14400*512 bf16
  u16* xtl = (u16*)p;         p += (size_t)29491200 * 2;
  u16* wkh = (u16*)p;         p += 131072 * 2;
  u16* wkl = (u16*)p;         p += 131072 * 2;
  u16* woh = (u16*)p;         p += 131072 * 2;
  u16* wol = (u16*)p;         p += 131072 * 2;
  float* xp = (float*)p;      p += (size_t)4 * 512 * 110 * 4;
  float* keyp = (float*)p;    p += (size_t)4 * 256 * 110 * 4;
  u16* vth = (u16*)p;         p += (size_t)4 * 256 * 128 * 2;
  u16* vtl = (u16*)p;         p += (size_t)4 * 256 * 128 * 2;
  u16* kth = (u16*)p;         p += (size_t)4 * 128 * 256 * 2;
  u16* ktl = (u16*)p;         p += (size_t)4 * 128 * 256 * 2;
  // aliases: xth/xtl (59MB each) are dead after gemm_kq.
  // first half -> agg hi/lo, second half -> kqT hi/lo (each 29.5MB)
  u16* aggh = xth;
  u16* kqth = xth + (size_t)14745600;
  u16* aggl = xtl;
  u16* kqtl = xtl + (size_t)14745600;

  // weight splits
  convert_w<<<512, 256, 0, stream>>>(Wk, wkh, wkl, 256 * 512);
  convert_w<<<512, 256, 0, stream>>>(Wo, woh, wol, 512 * 256);
  // X -> transposed bf16 hi/lo
  convert_t<512><<<dim3(225, 8, 4), 256, 0, stream>>>(x, xth, xtl);
  // pyramid-pool x (pooling commutes with 1x1 conv for value)
  pool_kernel<<<dim3(4 * 512), dim3(256), 0, stream>>>(x, xp);
  // valueT = split(conv_v(pooled x) + bv), s-padded
  value_kernel<<<dim3(4 * 128), dim3(256), 0, stream>>>(Wv, xp, bv, vth, vtl);
  // kq = relu(BN(conv_k(x)))  [split-bf16 MFMA]
  gemm_mfma<512, 256, true><<<dim3(225, 1, 4), 256, 0, stream>>>(
      wkh, wkl, xth, xtl, kq, bk, gamma, beta, mean, var);
  // kqT (query in A-fragment layout)
  convert_t<256><<<dim3(225, 4, 4), 256, 0, stream>>>(kq, kqth, kqtl);
  // key = ppm(kq) -> keypT split, s-padded
  pool_kernel<<<dim3(4 * 256), dim3(256), 0, stream>>>(kq, keyp);
  convert_key<<<dim3(4), dim3(256), 0, stream>>>(keyp, kth, ktl);
  // fused MFMA attention -> agg split bf16
  attn_mfma<<<dim3(225, 4), 256, 0, stream>>>(kqth, kqtl, kth, ktl, vth, vtl,
                                              aggh, aggl);
  // out = conv_out(agg) + bo  [split-bf16 MFMA]
  gemm_mfma<256, 512, false><<<dim3(225, 2, 4), 256, 0, stream>>>(
      woh, wol, aggh, aggl, out, bo, nullptr, nullptr, nullptr, nullptr);
}

// Round 4
// 548.688 us; speedup vs baseline: 1.6379x; 1.1291x over previous
//
#include <hip/hip_runtime.h>
#include <cstdint>
#include <cstddef>

#define HW 14400
#define WIDTH 120
#define S_TOT 110

typedef unsigned short u16;
typedef __attribute__((ext_vector_type(8))) short bf16x8;
typedef __attribute__((ext_vector_type(4))) float f32x4;

__device__ __forceinline__ u16 f2bf(float x) {
  unsigned u = __float_as_uint(x);
  unsigned r = (u + 0x7fffu + ((u >> 16) & 1u)) >> 16;
  return (u16)r;
}
__device__ __forceinline__ float bf2f(u16 h) {
  return __uint_as_float((unsigned)h << 16);
}

__device__ __forceinline__ void async16(void* lds, const void* g) {
  __builtin_amdgcn_global_load_lds(
      (const __attribute__((address_space(1))) void*)g,
      (__attribute__((address_space(3))) void*)lds, 16, 0, 0);
}

// ---------------------------------------------------------------------------
// Pyramid pooling: in [nplanes][14400] -> out [nplanes][110]
// ---------------------------------------------------------------------------
__global__ __launch_bounds__(256) void pool_kernel(const float* __restrict__ in,
                                                   float* __restrict__ outp) {
  __shared__ float part[576];
  const float* plane = in + (size_t)blockIdx.x * HW;
  int t = threadIdx.x;
  for (int bb = t; bb < 576; bb += 256) {
    int by = bb / 24, bx = bb % 24;
    const float* p0 = plane + (by * 5) * WIDTH + bx * 5;
    float s = 0.f;
#pragma unroll
    for (int yy = 0; yy < 5; ++yy)
#pragma unroll
      for (int xx = 0; xx < 5; ++xx) s += p0[yy * WIDTH + xx];
    part[bb] = s;
  }
  __syncthreads();
  if (t < S_TOT) {
    float s = 0.f;
    if (t == 0) {
      for (int i = 0; i < 576; ++i) s += part[i];
      s *= (1.f / 14400.f);
    } else if (t < 10) {
      int idx = t - 1, i = idx / 3, j = idx % 3;
      for (int a = 0; a < 8; ++a)
        for (int c = 0; c < 8; ++c) s += part[(i * 8 + a) * 24 + (j * 8 + c)];
      s *= (1.f / 1600.f);
    } else if (t < 46) {
      int idx = t - 10, i = idx / 6, j = idx % 6;
      for (int a = 0; a < 4; ++a)
        for (int c = 0; c < 4; ++c) s += part[(i * 4 + a) * 24 + (j * 4 + c)];
      s *= (1.f / 400.f);
    } else {
      int idx = t - 46, i = idx / 8, j = idx % 8;
      for (int a = 0; a < 3; ++a)
        for (int c = 0; c < 3; ++c) s += part[(i * 3 + a) * 24 + (j * 3 + c)];
      s *= (1.f / 225.f);
    }
    outp[(size_t)blockIdx.x * S_TOT + t] = s;
  }
}

// ---------------------------------------------------------------------------
// Split fp32 weight -> bf16 hi/lo (elementwise)
// ---------------------------------------------------------------------------
__global__ __launch_bounds__(256) void convert_w(const float* __restrict__ in,
                                                 u16* __restrict__ hi,
                                                 u16* __restrict__ lo, int n) {
  int i = blockIdx.x * 256 + threadIdx.x;
  if (i < n) {
    float v = in[i];
    u16 h = f2bf(v);
    hi[i] = h;
    lo[i] = f2bf(v - bf2f(h));
  }
}

// ---------------------------------------------------------------------------
// X [b][CIN][14400] fp32 -> XT hi/lo [b][14400][CIN] bf16 (transpose + split)
// ---------------------------------------------------------------------------
template <int CIN>
__global__ __launch_bounds__(256) void convert_t(const float* __restrict__ X,
                                                 u16* __restrict__ xth,
                                                 u16* __restrict__ xtl) {
  __shared__ float ls[64][65];
  int b = blockIdx.z;
  int n0 = blockIdx.x * 64, k0 = blockIdx.y * 64;
  int t = threadIdx.x;
  int rt = t >> 4, c4 = (t & 15) * 4;
#pragma unroll
  for (int rr = 0; rr < 4; ++rr) {
    int kk = rr * 16 + rt;
    float4 v = *(const float4*)&X[((size_t)(b * CIN + k0 + kk)) * HW + n0 + c4];
    ls[kk][c4] = v.x; ls[kk][c4 + 1] = v.y; ls[kk][c4 + 2] = v.z; ls[kk][c4 + 3] = v.w;
  }
  __syncthreads();
#pragma unroll
  for (int rr = 0; rr < 4; ++rr) {
    int nn = rr * 16 + rt;
    float v0 = ls[c4 + 0][nn], v1 = ls[c4 + 1][nn], v2 = ls[c4 + 2][nn], v3 = ls[c4 + 3][nn];
    ushort4 oh, ol;
    oh.x = f2bf(v0); ol.x = f2bf(v0 - bf2f(oh.x));
    oh.y = f2bf(v1); ol.y = f2bf(v1 - bf2f(oh.y));
    oh.z = f2bf(v2); ol.z = f2bf(v2 - bf2f(oh.z));
    oh.w = f2bf(v3); ol.w = f2bf(v3 - bf2f(oh.w));
    size_t idx = ((size_t)(b * HW + n0 + nn)) * CIN + k0 + c4;
    *(ushort4*)&xth[idx] = oh;
    *(ushort4*)&xtl[idx] = ol;
  }
}

// ---------------------------------------------------------------------------
// Split-bf16 MFMA GEMM:  C[b][m][n] = epi( sum_k A[m][k]*B[b][n][k] )
// (verified round 2)
// ---------------------------------------------------------------------------
template <int K, int M_TOT, bool BNRELU>
__global__ __launch_bounds__(256) void gemm_mfma(
    const u16* __restrict__ Ah, const u16* __restrict__ Al,
    const u16* __restrict__ Bh, const u16* __restrict__ Bl,
    float* __restrict__ C,
    const float* __restrict__ p0, const float* __restrict__ p1,
    const float* __restrict__ p2, const float* __restrict__ p3,
    const float* __restrict__ p4) {
  constexpr int NSTEP = K / 32;
  __shared__ alignas(16) u16 sAh[256 * 32];
  __shared__ alignas(16) u16 sAl[256 * 32];
  __shared__ alignas(16) u16 sBh[64 * 32];
  __shared__ alignas(16) u16 sBl[64 * 32];
  __shared__ float sP0[256], sP1[256];

  int t = threadIdx.x, w = t >> 6, l = t & 63;
  int b = blockIdx.z;
  int n0 = blockIdx.x * 64;
  int m0 = blockIdx.y * 256;

  if (BNRELU) {
    int m = m0 + t;
    float iv = p1[m] * rsqrtf(p4[m] + 1e-5f);
    sP0[t] = iv;
    sP1[t] = (p0[m] - p3[m]) * iv + p2[m];
  } else {
    sP0[t] = p0[m0 + t];
  }

  int crow = l >> 2;
  int cbyte = (l & 3) * 16;
  const size_t bOff = (size_t)b * HW;

  f32x4 acc[4][4];
#pragma unroll
  for (int i = 0; i < 4; ++i)
#pragma unroll
    for (int j = 0; j < 4; ++j) acc[i][j] = (f32x4){0.f, 0.f, 0.f, 0.f};

  int fr = l & 15, fk = (l >> 4) * 8;

  for (int ks = 0; ks < NSTEP; ++ks) {
    int k0 = ks * 32;
#pragma unroll
    for (int c = 0; c < 10; ++c) {
      int i = w * 10 + c;
      const u16* g;
      u16* d;
      if (i < 16) {
        g = Ah + (size_t)(m0 + i * 16 + crow) * K + k0;
        d = sAh + i * 512;
      } else if (i < 32) {
        g = Al + (size_t)(m0 + (i - 16) * 16 + crow) * K + k0;
        d = sAl + (i - 16) * 512;
      } else if (i < 36) {
        g = Bh + (bOff + n0 + (i - 32) * 16 + crow) * K + k0;
        d = sBh + (i - 32) * 512;
      } else {
        g = Bl + (bOff + n0 + (i - 36) * 16 + crow) * K + k0;
        d = sBl + (i - 36) * 512;
      }
      async16((char*)d, (const char*)g + cbyte);
    }
    __syncthreads();

    bf16x8 ah[4], al[4], bh[4], bl[4];
#pragma unroll
    for (int mt = 0; mt < 4; ++mt) {
      int r = w * 64 + mt * 16 + fr;
      ah[mt] = *(const bf16x8*)&sAh[r * 32 + fk];
      al[mt] = *(const bf16x8*)&sAl[r * 32 + fk];
    }
#pragma unroll
    for (int nt = 0; nt < 4; ++nt) {
      int r = nt * 16 + fr;
      bh[nt] = *(const bf16x8*)&sBh[r * 32 + fk];
      bl[nt] = *(const bf16x8*)&sBl[r * 32 + fk];
    }
#pragma unroll
    for (int mt = 0; mt < 4; ++mt)
#pragma unroll
      for (int nt = 0; nt < 4; ++nt) {
        acc[mt][nt] = __builtin_amdgcn_mfma_f32_16x16x32_bf16(ah[mt], bh[nt], acc[mt][nt], 0, 0, 0);
        acc[mt][nt] = __builtin_amdgcn_mfma_f32_16x16x32_bf16(ah[mt], bl[nt], acc[mt][nt], 0, 0, 0);
        acc[mt][nt] = __builtin_amdgcn_mfma_f32_16x16x32_bf16(al[mt], bh[nt], acc[mt][nt], 0, 0, 0);
      }
    __syncthreads();
  }

#pragma unroll
  for (int mt = 0; mt < 4; ++mt) {
    int lmBase = w * 64 + mt * 16 + (l >> 4) * 4;
#pragma unroll
    for (int nt = 0; nt < 4; ++nt) {
      int n = n0 + nt * 16 + fr;
#pragma unroll
      for (int r = 0; r < 4; ++r) {
        int lm = lmBase + r;
        float v = acc[mt][nt][r];
        if (BNRELU)
          v = fmaxf(v * sP0[lm] + sP1[lm], 0.f);
        else
          v = v + sP0[lm];
        C[((size_t)(b * M_TOT + m0 + lm)) * HW + n] = v;
      }
    }
  }
}

// ---------------------------------------------------------------------------
// valueT[b][cv][128] hi/lo = Wv[cv,:] . xp[b,:,s] + bv[cv]  (s>=110 -> 0)
// ---------------------------------------------------------------------------
__global__ __launch_bounds__(256) void value_kernel(
    const float* __restrict__ Wv, const float* __restrict__ xp,
    const float* __restrict__ bv, u16* __restrict__ vth,
    u16* __restrict__ vtl) {
  int b = blockIdx.x >> 7, s = blockIdx.x & 127;
  int t = threadIdx.x;
  size_t o = ((size_t)(b * 256 + t)) * 128 + s;
  if (s >= S_TOT) { vth[o] = 0; vtl[o] = 0; return; }
  __shared__ float xs[512];
  for (int i = t; i < 512; i += 256) xs[i] = xp[((size_t)b * 512 + i) * S_TOT + s];
  __syncthreads();
  float accv = 0.f;
  const float* wv = Wv + (size_t)t * 512;
  for (int k = 0; k < 512; k += 4) {
    float4 w4 = *(const float4*)&wv[k];
    accv += w4.x * xs[k] + w4.y * xs[k + 1] + w4.z * xs[k + 2] + w4.w * xs[k + 3];
  }
  accv += bv[t];
  u16 h = f2bf(accv);
  vth[o] = h;
  vtl[o] = f2bf(accv - bf2f(h));
}

// ---------------------------------------------------------------------------
// keypT[b][128][256] hi/lo from keyp [b][256][110] fp32 (s>=110 -> 0)
// ---------------------------------------------------------------------------
__global__ __launch_bounds__(256) void convert_key(const float* __restrict__ keyp,
                                                   u16* __restrict__ kth,
                                                   u16* __restrict__ ktl) {
  int b = blockIdx.x;
  int t = threadIdx.x;
  for (int i = t; i < 128 * 256; i += 256) {
    int s = i >> 8, c = i & 255;
    float v = (s < S_TOT) ? keyp[((size_t)(b * 256 + c)) * S_TOT + s] : 0.f;
    u16 h = f2bf(v);
    size_t o = ((size_t)(b * 128 + s)) * 256 + c;
    kth[o] = h;
    ktl[o] = f2bf(v - bf2f(h));
  }
}

// ---------------------------------------------------------------------------
// MFMA attention v2. Per block: 64 pixels, 4 waves.
// Stage 1: S = Q K^T. K staged to LDS in MFMA-fragment order via
// global_load_lds (double-buffered, one barrier per 32-c chunk); Q direct
// global loads (2 frags/chunk). Softmax fully in-wave. P (normalized,
// split bf16) -> LDS [64][136] (s padded to 128; pad lanes get exp->0).
// Stage 2: agg^T tiles: A=V (direct L2 loads, 4 nt per wave), B=P (LDS).
// D: rows=cv (q,r), cols=pix (fr) -> ushort4 vector stores, agg layout
// [b][pix][256] split hi/lo (gemm_out's B operand).
// ---------------------------------------------------------------------------
__global__ __launch_bounds__(256) void attn_mfma(
    const u16* __restrict__ qh, const u16* __restrict__ ql,
    const u16* __restrict__ kh, const u16* __restrict__ kl,
    const u16* __restrict__ vh, const u16* __restrict__ vl,
    u16* __restrict__ aggh, u16* __restrict__ aggl) {
  // union: stage1 K dbuf = 2 x 8192 u16 (32KB); then P hi[0,8704) lo[8704,17408)
  __shared__ alignas(16) u16 lds[17408];
  int b = blockIdx.y, pix0 = blockIdx.x * 64;
  int t = threadIdx.x, w = t >> 6, l = t & 63;
  int fr = l & 15, q = l >> 4;

  const u16* kbase_h = kh + (size_t)b * 128 * 256;
  const u16* kbase_l = kl + (size_t)b * 128 * 256;

  // ---- stage 1: scores [16 pix][128 s] per wave ----
  f32x4 acc[8];
#pragma unroll
  for (int st = 0; st < 8; ++st) acc[st] = (f32x4){0.f, 0.f, 0.f, 0.f};

  const u16* qbh = qh + ((size_t)(b * HW + pix0 + w * 16 + fr)) * 256 + q * 8;
  const u16* qbl = ql + ((size_t)(b * HW + pix0 + w * 16 + fr)) * 256 + q * 8;

  // stage K chunk (32 c) into buf: fragment-major [hi/lo][st][lane][8]
  auto stageK = [&](int ks, int buf) {
    int c0 = ks * 32;
#pragma unroll
    for (int j = 0; j < 4; ++j) {
      int i = t + j * 256;
      int half = i >> 9;  // 0: Kh, 1: Kl
      int idx = i & 511;
      int st = idx >> 6, ll = idx & 63;
      const u16* src = (half ? kbase_l : kbase_h) +
                       (st * 16 + (ll & 15)) * 256 + c0 + (ll >> 4) * 8;
      async16(&lds[buf * 8192 + half * 4096 + idx * 8], src);
    }
  };

  stageK(0, 0);
  for (int ks = 0; ks < 8; ++ks) {
    __syncthreads();  // buf[ks&1] ready (drains global_load_lds)
    if (ks < 7) stageK(ks + 1, (ks + 1) & 1);
    bf16x8 ah = *(const bf16x8*)(qbh + ks * 32);
    bf16x8 al = *(const bf16x8*)(qbl + ks * 32);
    const u16* kb = &lds[(ks & 1) * 8192 + l * 8];
#pragma unroll
    for (int st = 0; st < 8; ++st) {
      bf16x8 bh = *(const bf16x8*)(kb + st * 512);
      bf16x8 bl = *(const bf16x8*)(kb + 4096 + st * 512);
      acc[st] = __builtin_amdgcn_mfma_f32_16x16x32_bf16(ah, bh, acc[st], 0, 0, 0);
      acc[st] = __builtin_amdgcn_mfma_f32_16x16x32_bf16(ah, bl, acc[st], 0, 0, 0);
      acc[st] = __builtin_amdgcn_mfma_f32_16x16x32_bf16(al, bh, acc[st], 0, 0, 0);
    }
  }

  // scale + mask (col s = st*16+fr; valid s < 110)
#pragma unroll
  for (int st = 0; st < 8; ++st)
#pragma unroll
    for (int r = 0; r < 4; ++r) acc[st][r] *= 0.0625f;
  if (fr >= 14) {
#pragma unroll
    for (int r = 0; r < 4; ++r) acc[6][r] = -1e30f;
  }
#pragma unroll
  for (int r = 0; r < 4; ++r) acc[7][r] = -1e30f;

  // in-wave softmax per pixel row (row = q*4+r; cols over fr lanes + st regs)
#pragma unroll
  for (int r = 0; r < 4; ++r) {
    float m = -1e30f;
#pragma unroll
    for (int st = 0; st < 8; ++st) m = fmaxf(m, acc[st][r]);
    m = fmaxf(m, __shfl_xor(m, 1));
    m = fmaxf(m, __shfl_xor(m, 2));
    m = fmaxf(m, __shfl_xor(m, 4));
    m = fmaxf(m, __shfl_xor(m, 8));
    float s = 0.f;
#pragma unroll
    for (int st = 0; st < 8; ++st) {
      float e = __expf(acc[st][r] - m);
      acc[st][r] = e;
      s += e;
    }
    s += __shfl_xor(s, 1);
    s += __shfl_xor(s, 2);
    s += __shfl_xor(s, 4);
    s += __shfl_xor(s, 8);
    float inv = 1.f / s;
#pragma unroll
    for (int st = 0; st < 8; ++st) acc[st][r] *= inv;
  }

  __syncthreads();  // all stage-1 LDS reads done before P overwrites

  // write P (normalized, split bf16); pad region s>=110 holds exp->0
  int prow = w * 16 + q * 4;
#pragma unroll
  for (int st = 0; st < 8; ++st) {
    int s = st * 16 + fr;
#pragma unroll
    for (int r = 0; r < 4; ++r) {
      float v = acc[st][r];
      u16 h = f2bf(v);
      lds[(prow + r) * 136 + s] = h;
      lds[8704 + (prow + r) * 136 + s] = f2bf(v - bf2f(h));
    }
  }
  __syncthreads();

  // ---- stage 2: agg tiles, A=V (global/L2), B=P (LDS) ----
  f32x4 oacc[4][4];
#pragma unroll
  for (int nt = 0; nt < 4; ++nt)
#pragma unroll
    for (int pt = 0; pt < 4; ++pt) oacc[nt][pt] = (f32x4){0.f, 0.f, 0.f, 0.f};

  const u16* vbh = vh + ((size_t)(b * 256 + w * 64 + fr)) * 128 + q * 8;
  const u16* vbl = vl + ((size_t)(b * 256 + w * 64 + fr)) * 128 + q * 8;

#pragma unroll
  for (int kc = 0; kc < 4; ++kc) {
    bf16x8 ph[4], pl[4];
#pragma unroll
    for (int pt = 0; pt < 4; ++pt) {
      ph[pt] = *(const bf16x8*)&lds[(pt * 16 + fr) * 136 + kc * 32 + q * 8];
      pl[pt] = *(const bf16x8*)&lds[8704 + (pt * 16 + fr) * 136 + kc * 32 + q * 8];
    }
#pragma unroll
    for (int nt = 0; nt < 4; ++nt) {
      bf16x8 a_h = *(const bf16x8*)(vbh + (size_t)nt * 16 * 128 + kc * 32);
      bf16x8 a_l = *(const bf16x8*)(vbl + (size_t)nt * 16 * 128 + kc * 32);
#pragma unroll
      for (int pt = 0; pt < 4; ++pt) {
        oacc[nt][pt] = __builtin_amdgcn_mfma_f32_16x16x32_bf16(a_h, ph[pt], oacc[nt][pt], 0, 0, 0);
        oacc[nt][pt] = __builtin_amdgcn_mfma_f32_16x16x32_bf16(a_h, pl[pt], oacc[nt][pt], 0, 0, 0);
        oacc[nt][pt] = __builtin_amdgcn_mfma_f32_16x16x32_bf16(a_l, ph[pt], oacc[nt][pt], 0, 0, 0);
      }
    }
  }

  // stores: pix = pix0 + pt*16 + fr, cv = (w*4+nt)*16 + q*4 + r (r contiguous)
#pragma unroll
  for (int nt = 0; nt < 4; ++nt) {
#pragma unroll
    for (int pt = 0; pt < 4; ++pt) {
      ushort4 oh, ol;
      float v0 = oacc[nt][pt][0], v1 = oacc[nt][pt][1];
      float v2 = oacc[nt][pt][2], v3 = oacc[nt][pt][3];
      oh.x = f2bf(v0); ol.x = f2bf(v0 - bf2f(oh.x));
      oh.y = f2bf(v1); ol.y = f2bf(v1 - bf2f(oh.y));
      oh.z = f2bf(v2); ol.z = f2bf(v2 - bf2f(oh.z));
      oh.w = f2bf(v3); ol.w = f2bf(v3 - bf2f(oh.w));
      size_t o = ((size_t)(b * HW + pix0 + pt * 16 + fr)) * 256 + (w * 4 + nt) * 16 + q * 4;
      *(ushort4*)&aggh[o] = oh;
      *(ushort4*)&aggl[o] = ol;
    }
  }
}

extern "C" void kernel_launch(void* const* d_in, const int* in_sizes, int n_in,
                              void* d_out, int out_size, void* d_ws, size_t ws_size,
                              hipStream_t stream) {
  (void)in_sizes; (void)n_in; (void)out_size; (void)ws_size;
  const float* x     = (const float*)d_in[0];
  const float* Wk    = (const float*)d_in[1];
  const float* bk    = (const float*)d_in[2];
  const float* gamma = (const float*)d_in[3];
  const float* beta  = (const float*)d_in[4];
  const float* mean  = (const float*)d_in[5];
  const float* var   = (const float*)d_in[6];
  const float* Wv    = (const float*)d_in[7];
  const float* bv    = (const float*)d_in[8];
  const float* Wo    = (const float*)d_in[9];
  const float* bo    = (const float*)d_in[10];
  float* out = (float*)d_out;

  char* p = (char*)d_ws;
  float* kq = (float*)p;      p += (size_t)14745600 * 4;   // 4*256*14400 fp32
  u16* xth = (u16*)p;         p += (size_t)29491200 * 2;   // 4*14400*512 bf16
  u16* xtl = (u16*)p;         p += (size_t)29491200 * 2;
  u16* wkh = (u16*)p;         p += 131072 * 2;
  u16* wkl = (u16*)p;         p += 131072 * 2;
  u16* woh = (u16*)p;         p += 131072 * 2;
  u16* wol = (u16*)p;         p += 131072 * 2;
  float* xp = (float*)p;      p += (size_t)4 * 512 * 110 * 4;
  float* keyp = (float*)p;    p += (size_t)4 * 256 * 110 * 4;
  u16* vth = (u16*)p;         p += (size_t)4 * 256 * 128 * 2;
  u16* vtl = (u16*)p;         p += (size_t)4 * 256 * 128 * 2;
  u16* kth = (u16*)p;         p += (size_t)4 * 128 * 256 * 2;
  u16* ktl = (u16*)p;         p += (size_t)4 * 128 * 256 * 2;
  // aliases: xth/xtl (59MB each) are dead after gemm_kq.
  // first half -> agg hi/lo, second half -> kqT hi/lo (each 29.5MB)
  u16* aggh = xth;
  u16* kqth = xth + (size_t)14745600;
  u16* aggl = xtl;
  u16* kqtl = xtl + (size_t)14745600;

  // weight splits
  convert_w<<<512, 256, 0, stream>>>(Wk, wkh, wkl, 256 * 512);
  convert_w<<<512, 256, 0, stream>>>(Wo, woh, wol, 512 * 256);
  // X -> transposed bf16 hi/lo
  convert_t<512><<<dim3(225, 8, 4), 256, 0, stream>>>(x, xth, xtl);
  // pyramid-pool x (pooling commutes with 1x1 conv for value)
  pool_kernel<<<dim3(4 * 512), dim3(256), 0, stream>>>(x, xp);
  // valueT = split(conv_v(pooled x) + bv), s-padded
  value_kernel<<<dim3(4 * 128), dim3(256), 0, stream>>>(Wv, xp, bv, vth, vtl);
  // kq = relu(BN(conv_k(x)))  [split-bf16 MFMA]
  gemm_mfma<512, 256, true><<<dim3(225, 1, 4), 256, 0, stream>>>(
      wkh, wkl, xth, xtl, kq, bk, gamma, beta, mean, var);
  // kqT (query in A-fragment layout)
  convert_t<256><<<dim3(225, 4, 4), 256, 0, stream>>>(kq, kqth, kqtl);
  // key = ppm(kq) -> keypT split, s-padded
  pool_kernel<<<dim3(4 * 256), dim3(256), 0, stream>>>(kq, keyp);
  convert_key<<<dim3(4), dim3(256), 0, stream>>>(keyp, kth, ktl);
  // fused MFMA attention -> agg split bf16
  attn_mfma<<<dim3(225, 4), 256, 0, stream>>>(kqth, kqtl, kth, ktl, vth, vtl,
                                              aggh, aggl);
  // out = conv_out(agg) + bo  [split-bf16 MFMA]
  gemm_mfma<256, 512, false><<<dim3(225, 2, 4), 256, 0, stream>>>(
      woh, wol, aggh, aggl, out, bo, nullptr, nullptr, nullptr, nullptr);
}